// Round 19
// baseline (199.456 us; speedup 1.0000x reference)
//
#include <hip/hip_runtime.h>
#include <cstdint>
#include <cstddef>

#define ALPHA 0.01f
#define A1    0.99f
#define B_    8
#define S_    2048
#define H_    2048
#define NCH   16     // chunks along S (scan)
#define CL    128    // chunk length (scan)
#define NKT   32     // K tiles in GEMM (2048/64)

typedef __attribute__((ext_vector_type(8))) short bf16x8;
typedef __attribute__((ext_vector_type(4))) float f32x4;

__device__ __forceinline__ unsigned short f2bf(float f) {
    unsigned int u = __float_as_uint(f);
    u += 0x7FFFu + ((u >> 16) & 1u);   // round-to-nearest-even
    return (unsigned short)(u >> 16);
}

__device__ __forceinline__ void gld16(const void* g, void* l) {
    __builtin_amdgcn_global_load_lds(
        (const __attribute__((address_space(1))) unsigned int*)g,
        (__attribute__((address_space(3))) unsigned int*)l, 16, 0, 0);
}

// ---------------- W cast: f32 -> bf16 ----------------
__global__ void ema_cast_w(const float* __restrict__ W, short* __restrict__ Wb) {
    int i = (blockIdx.x * 256 + threadIdx.x) * 4;
    float4 v = *(const float4*)(W + i);
    short4 o;
    o.x = (short)f2bf(v.x);
    o.y = (short)f2bf(v.y);
    o.z = (short)f2bf(v.z);
    o.w = (short)f2bf(v.w);
    *(short4*)(Wb + i) = o;
}

// ---------------- pass 1: chunk-local EMA carries (float2, 2 chains/thread) ----
// 512 blocks: b(8) x c(16) x hg(4) -> 8 waves/CU
__global__ __launch_bounds__(256) void ema_carry_kernel(
        const float* __restrict__ x, float* __restrict__ carry) {
    int bid = blockIdx.x;
    int hg = bid & 3;
    int c  = (bid >> 2) & 15;
    int b  = bid >> 6;
    int h0 = (hg << 9) + (threadIdx.x << 1);
    const float2* px = (const float2*)(x + ((size_t)(b * S_) + (size_t)c * CL) * H_ + h0);
    const int STR = H_ / 2;               // float2 stride per sequence step
    float s0, s1;
    int i0;
    if (c == 0) { float2 v = px[0]; s0 = v.x; s1 = v.y; i0 = 1; }
    else        { s0 = 0.f; s1 = 0.f;                   i0 = 0; }
    #pragma unroll 8
    for (int i = i0; i < CL; ++i) {
        float2 v = px[(size_t)i * STR];
        s0 = fmaf(A1, s0, ALPHA * v.x);
        s1 = fmaf(A1, s1, ALPHA * v.y);
    }
    *(float2*)(carry + ((b << 4) + c) * H_ + h0) = (float2){s0, s1};
}

// ---------------- pass 2: apply carry-in, rescan, write packed bf16 s ----------
__global__ __launch_bounds__(256) void ema_apply_kernel(
        const float* __restrict__ x, const float* __restrict__ carry,
        unsigned short* __restrict__ sb) {
    int bid = blockIdx.x;
    int hg = bid & 3;
    int c  = (bid >> 2) & 15;
    int b  = bid >> 6;
    int h0 = (hg << 9) + (threadIdx.x << 1);

    float A128 = A1;                      // 0.99^128 via 7 squarings
    #pragma unroll
    for (int q = 0; q < 7; ++q) A128 *= A128;

    float c0 = 0.f, c1 = 0.f, f = 1.f;
    for (int j = c - 1; j >= 0; --j) {    // <=15 lookback steps (L2-resident)
        float2 cv = *(const float2*)(carry + ((b << 4) + j) * H_ + h0);
        c0 = fmaf(cv.x, f, c0);
        c1 = fmaf(cv.y, f, c1);
        f *= A128;
    }

    size_t base = ((size_t)(b * S_) + (size_t)c * CL) * H_ + h0;
    const float2* px = (const float2*)(x + base);
    unsigned int*  pu = (unsigned int*)(sb + base);
    const int STR = H_ / 2;
    float s0, s1;
    int i0;
    if (c == 0) {
        float2 v = px[0]; s0 = v.x; s1 = v.y;
        pu[0] = (unsigned int)f2bf(s0) | ((unsigned int)f2bf(s1) << 16);
        i0 = 1;
    } else { s0 = c0; s1 = c1; i0 = 0; }
    #pragma unroll 8
    for (int i = i0; i < CL; ++i) {
        float2 v = px[(size_t)i * STR];
        s0 = fmaf(A1, s0, ALPHA * v.x);
        s1 = fmaf(A1, s1, ALPHA * v.y);
        pu[(size_t)i * STR] = (unsigned int)f2bf(s0) | ((unsigned int)f2bf(s1) << 16);
    }
}

// ---------------- GEMM: 256x256 tile, BK=64, 4 FAT waves (128x128/wave) -------
// out[m,n] = sum_k s[m,k]*W[n,k] + bias[n].  M=16384 N=2048 K=2048.
// Round-12 4-BAR cadence, but 4 waves x 128x128 instead of 8 x 128x64:
// LDS fragment traffic drops 192->128 KB/tile (below the 620-cy MFMA pipe),
// making the matrix pipe the binding resource. acc[8][8] = 256 VGPR,
// 1 wave/SIMD (launch_bounds(256,1)).
// B storage LINEAR (slot = wn*2+nh); staging groups B1st={0,2}, B2nd={1,3}
// match phase liveness. A quarter permutation [Q0,Q2,Q1,Q3] unchanged.
// Staging issues are 4KB (2 gld16 per 8KB slot) -> all VMW counts double (12).
// WAR ledger re-verified: every staged region's last reader MM issued >=1 BAR
// before the staging writes can land.
// Swizzle: byte ^= ((storage_row & 7) << 4); both-sides. Conflict-free (r5).

#define BAR __builtin_amdgcn_s_barrier()
#define VMW(n) asm volatile("s_waitcnt vmcnt(" #n ")" ::: "memory")

#define STGA(i, kt, buf) do {                                                      \
    gld16(gA[i] + (size_t)(kt) * 128,            &ldsA[buf][((i) << 12) + (w << 9)]); \
    gld16(gA[i] + (size_t)(kt) * 128 + 32 * K2,  &ldsA[buf][((i) << 12) + 2048 + (w << 9)]); } while (0)
#define STGB(i, kt, buf) do {                                                      \
    gld16(gB[i] + (size_t)(kt) * 128,            &ldsB[buf][((i) << 12) + (w << 9)]); \
    gld16(gB[i] + (size_t)(kt) * 128 + 32 * K2,  &ldsB[buf][((i) << 12) + 2048 + (w << 9)]); } while (0)

#define LDA(dst, mh) do { int ra_ = (wm << 1) | (mh);                              \
    const char* base_ = (const char*)&ldsA[cur][0]                                 \
        + (((((ra_ & 1) << 1) | (ra_ >> 1))) << 13) + laneRow;                     \
    _Pragma("unroll") for (int m_ = 0; m_ < 4; ++m_) {                             \
        dst[m_][0] = *(const bf16x8*)(base_ + (m_ << 11) + ck0);                   \
        dst[m_][1] = *(const bf16x8*)(base_ + (m_ << 11) + ck1); } } while (0)

#define LDB(dst, nh) do { int sl_ = (wn << 1) | (nh);                              \
    const char* base_ = (const char*)&ldsB[cur][0] + (sl_ << 13) + laneRow;        \
    _Pragma("unroll") for (int n_ = 0; n_ < 4; ++n_) {                             \
        dst[n_][0] = *(const bf16x8*)(base_ + (n_ << 11) + ck0);                   \
        dst[n_][1] = *(const bf16x8*)(base_ + (n_ << 11) + ck1); } } while (0)

#define MM(Asrc, Bsrc, mh, nh) do { __builtin_amdgcn_s_setprio(1);                 \
    _Pragma("unroll") for (int m_ = 0; m_ < 4; ++m_)                               \
    _Pragma("unroll") for (int n_ = 0; n_ < 4; ++n_)                               \
    _Pragma("unroll") for (int k_ = 0; k_ < 2; ++k_)                               \
        acc[(mh) * 4 + m_][(nh) * 4 + n_] = __builtin_amdgcn_mfma_f32_16x16x32_bf16( \
            Asrc[m_][k_], Bsrc[n_][k_], acc[(mh) * 4 + m_][(nh) * 4 + n_], 0, 0, 0); \
    __builtin_amdgcn_s_setprio(0); } while (0)

__global__ __launch_bounds__(256, 1) void ema_gemm_kernel(
        const short* __restrict__ Sb, const short* __restrict__ Wb,
        const float* __restrict__ bias, float* __restrict__ out) {
    __shared__ short ldsA[2][16384];   // 64 KiB
    __shared__ short ldsB[2][16384];   // 64 KiB

    int bid = blockIdx.x;
    int swz = ((bid & 7) << 6) | (bid >> 3);   // XCD swizzle, bijective (512 % 8 == 0)
    int tm = swz >> 3;                 // 0..63
    int tn = swz & 7;                  // 0..7

    int tid  = threadIdx.x;
    int lane = tid & 63;
    int w    = tid >> 6;               // 0..3
    int wm   = w >> 1;                 // 0..1
    int wn   = w & 1;                  // 0..1

    const int K2 = H_ * 2;             // row stride in bytes (4096)
    int rowA = tm << 8;
    int rowB = tn << 8;

    // ---- staging source pointers (per-lane, pre-swizzled global addresses) ----
    // staged row within 4KB issue = 8w + (lane>>3) in 0..31; row&7 = (lane>>3)&7
    int rowoff = (w << 3) + (lane >> 3);
    int colb   = (((lane & 7) ^ (lane >> 3)) << 4);      // inverse-swizzled k-byte
    const char* SbB = (const char*)Sb;
    const char* WbB = (const char*)Wb;
    const char* gA[4];
    const char* gB[4];
    #pragma unroll
    for (int i = 0; i < 4; ++i) {
        int lq = ((i & 1) << 1) | (i >> 1);              // storage slot -> logical A quarter
        gA[i] = SbB + (size_t)(rowA + lq * 64 + rowoff) * K2 + colb;
        gB[i] = WbB + (size_t)(rowB + i * 64 + rowoff) * K2 + colb;   // linear
    }

    // ---- fragment ds_read offsets (swizzled) ----
    int laneRow = (lane & 15) << 7;
    int ck0 = (((lane >> 4)) ^ (lane & 7)) << 4;
    int ck1 = ((4 + (lane >> 4)) ^ (lane & 7)) << 4;

    f32x4 acc[8][8];
    #pragma unroll
    for (int i = 0; i < 8; ++i)
        #pragma unroll
        for (int j = 0; j < 8; ++j)
            acc[i][j] = (f32x4){0.f, 0.f, 0.f, 0.f};
    bf16x8 Af0[4][2], Af1[4][2], Bf0[4][2], Bf1[4][2];

    int colg = (tn << 8) + (wn << 7) + (lane & 15);
    float bb[8];
    #pragma unroll
    for (int n = 0; n < 8; ++n) bb[n] = bias[colg + (n << 4)];

    // ---- prologue: tile0 full (16 issues) + tile1 A1st/B1st (8); VMW(12) ----
    STGA(0, 0, 0); STGA(1, 0, 0); STGB(0, 0, 0); STGB(2, 0, 0);   // A1st(0), B1st(0)
    STGA(2, 0, 0); STGA(3, 0, 0); STGB(1, 0, 0); STGB(3, 0, 0);   // A2nd(0), B2nd(0)
    STGA(0, 1, 1); STGA(1, 1, 1); STGB(0, 1, 1); STGB(2, 1, 1);   // A1st(1), B1st(1)
    VMW(12);
    BAR;

    for (int t = 0; t < NKT; ++t) {
        int cur = t & 1, nxt = cur ^ 1;
        bool i01 = (t < NKT - 1), i23 = (t < NKT - 2);
        // phase 0: reads A-q(mh0) + B-slot(wn,0); stage A2nd(t+1); VMW; BAR; MM00
        LDA(Af0, 0); LDB(Bf0, 0);
        if (i01) { STGA(2, t + 1, nxt); STGA(3, t + 1, nxt); VMW(12); }
        BAR;
        MM(Af0, Bf0, 0, 0);
        // phase 1: reads B-slot(wn,1); stage B2nd(t+1); BAR; MM01
        LDB(Bf1, 1);
        if (i01) { STGB(1, t + 1, nxt); STGB(3, t + 1, nxt); }
        BAR;
        MM(Af0, Bf1, 0, 1);
        // phase 2: reads A-q(mh1); stage A1st(t+2) into dead cur; BAR; MM10
        LDA(Af1, 1);
        if (i23) { STGA(0, t + 2, cur); STGA(1, t + 2, cur); }
        BAR;
        MM(Af1, Bf0, 1, 0);
        // phase 3: stage B1st(t+2) into dead cur; VMW; BAR; MM11
        if (i23)                { STGB(0, t + 2, cur); STGB(2, t + 2, cur); VMW(12); }
        else if (t == NKT - 2)  { VMW(0); }   // entering last tile: drain
        BAR;
        MM(Af1, Bf1, 1, 1);
    }

    // ---- epilogue: C/D layout col=lane&15, row=(lane>>4)*4+q ----
    int rowg = (tm << 8) + (wm << 7) + ((lane >> 4) << 2);
    #pragma unroll
    for (int m = 0; m < 8; ++m) {
        #pragma unroll
        for (int n = 0; n < 8; ++n) {
            int c = colg + (n << 4);
            size_t rb = (size_t)(rowg + (m << 4)) << 11;
            #pragma unroll
            for (int q = 0; q < 4; ++q)
                out[rb + ((size_t)q << 11) + c] = acc[m][n][q] + bb[n];
        }
    }
}

extern "C" void kernel_launch(void* const* d_in, const int* in_sizes, int n_in,
                              void* d_out, int out_size, void* d_ws, size_t ws_size,
                              hipStream_t stream) {
    const float* x    = (const float*)d_in[0];   // [B,S,H] f32
    const float* W    = (const float*)d_in[1];   // [H,H] f32
    const float* bias = (const float*)d_in[2];   // [H] f32
    float* out = (float*)d_out;                  // [B,S,H] f32

    char* ws = (char*)d_ws;
    size_t s_bytes = (size_t)B_ * S_ * H_ * 2;   // 67.1 MB bf16 s
    size_t w_bytes = (size_t)H_ * H_ * 2;        // 8.4 MB bf16 W
    unsigned short* s_bf  = (unsigned short*)ws;
    short*          w_bf  = (short*)(ws + s_bytes);
    float*          carry = (float*)(ws + s_bytes + w_bytes);  // 8*16*2048 f32 = 1 MB

    ema_cast_w<<<(H_ * H_) / 1024, 256, 0, stream>>>(W, w_bf);
    ema_carry_kernel<<<B_ * NCH * (H_ / 512), 256, 0, stream>>>(x, carry);
    ema_apply_kernel<<<B_ * NCH * (H_ / 512), 256, 0, stream>>>(x, carry, s_bf);
    ema_gemm_kernel<<<(16384 / 256) * (2048 / 256), 256, 0, stream>>>(
        (const short*)s_bf, w_bf, bias, out);
}

// Round 20
// 181.187 us; speedup vs baseline: 1.1008x; 1.1008x over previous
//
#include <hip/hip_runtime.h>
#include <cstdint>
#include <cstddef>

#define ALPHA 0.01f
#define A1    0.99f
#define B_    8
#define S_    2048
#define H_    2048
#define NCH   16     // chunks along S (scan)
#define CL    128    // chunk length (scan)
#define NKT   32     // K tiles in GEMM (2048/64)

typedef __attribute__((ext_vector_type(8))) short bf16x8;
typedef __attribute__((ext_vector_type(4))) float f32x4;

__device__ __forceinline__ unsigned short f2bf(float f) {
    unsigned int u = __float_as_uint(f);
    u += 0x7FFFu + ((u >> 16) & 1u);   // round-to-nearest-even
    return (unsigned short)(u >> 16);
}

__device__ __forceinline__ void gld16(const void* g, void* l) {
    __builtin_amdgcn_global_load_lds(
        (const __attribute__((address_space(1))) unsigned int*)g,
        (__attribute__((address_space(3))) unsigned int*)l, 16, 0, 0);
}

// ---------------- W cast: f32 -> bf16 ----------------
__global__ void ema_cast_w(const float* __restrict__ W, short* __restrict__ Wb) {
    int i = (blockIdx.x * 256 + threadIdx.x) * 4;
    float4 v = *(const float4*)(W + i);
    short4 o;
    o.x = (short)f2bf(v.x);
    o.y = (short)f2bf(v.y);
    o.z = (short)f2bf(v.z);
    o.w = (short)f2bf(v.w);
    *(short4*)(Wb + i) = o;
}

// ---------------- pass 1: chunk-local EMA carries (float2, 2 chains/thread) ----
// 512 blocks: b(8) x c(16) x hg(4) -> 8 waves/CU
__global__ __launch_bounds__(256) void ema_carry_kernel(
        const float* __restrict__ x, float* __restrict__ carry) {
    int bid = blockIdx.x;
    int hg = bid & 3;
    int c  = (bid >> 2) & 15;
    int b  = bid >> 6;
    int h0 = (hg << 9) + (threadIdx.x << 1);
    const float2* px = (const float2*)(x + ((size_t)(b * S_) + (size_t)c * CL) * H_ + h0);
    const int STR = H_ / 2;               // float2 stride per sequence step
    float s0, s1;
    int i0;
    if (c == 0) { float2 v = px[0]; s0 = v.x; s1 = v.y; i0 = 1; }
    else        { s0 = 0.f; s1 = 0.f;                   i0 = 0; }
    #pragma unroll 8
    for (int i = i0; i < CL; ++i) {
        float2 v = px[(size_t)i * STR];
        s0 = fmaf(A1, s0, ALPHA * v.x);
        s1 = fmaf(A1, s1, ALPHA * v.y);
    }
    *(float2*)(carry + ((b << 4) + c) * H_ + h0) = (float2){s0, s1};
}

// ---------------- pass 2: apply carry-in, rescan, write packed bf16 s ----------
__global__ __launch_bounds__(256) void ema_apply_kernel(
        const float* __restrict__ x, const float* __restrict__ carry,
        unsigned short* __restrict__ sb) {
    int bid = blockIdx.x;
    int hg = bid & 3;
    int c  = (bid >> 2) & 15;
    int b  = bid >> 6;
    int h0 = (hg << 9) + (threadIdx.x << 1);

    float A128 = A1;                      // 0.99^128 via 7 squarings
    #pragma unroll
    for (int q = 0; q < 7; ++q) A128 *= A128;

    float c0 = 0.f, c1 = 0.f, f = 1.f;
    for (int j = c - 1; j >= 0; --j) {    // <=15 lookback steps (L2-resident)
        float2 cv = *(const float2*)(carry + ((b << 4) + j) * H_ + h0);
        c0 = fmaf(cv.x, f, c0);
        c1 = fmaf(cv.y, f, c1);
        f *= A128;
    }

    size_t base = ((size_t)(b * S_) + (size_t)c * CL) * H_ + h0;
    const float2* px = (const float2*)(x + base);
    unsigned int*  pu = (unsigned int*)(sb + base);
    const int STR = H_ / 2;
    float s0, s1;
    int i0;
    if (c == 0) {
        float2 v = px[0]; s0 = v.x; s1 = v.y;
        pu[0] = (unsigned int)f2bf(s0) | ((unsigned int)f2bf(s1) << 16);
        i0 = 1;
    } else { s0 = c0; s1 = c1; i0 = 0; }
    #pragma unroll 8
    for (int i = i0; i < CL; ++i) {
        float2 v = px[(size_t)i * STR];
        s0 = fmaf(A1, s0, ALPHA * v.x);
        s1 = fmaf(A1, s1, ALPHA * v.y);
        pu[(size_t)i * STR] = (unsigned int)f2bf(s0) | ((unsigned int)f2bf(s1) << 16);
    }
}

// ---------------- GEMM: 256x256 tile, BK=64, 8 waves ---------------------------
// out[m,n] = sum_k s[m,k]*W[n,k] + bias[n].  M=16384 N=2048 K=2048.
// FINAL CHAMPION (round 12 cadence; reproduced r15/r16/r18 at 135.5-136.5 us,
// 42.5% MfmaUtil, 0 conflicts): 4 BAR/tile, no post-MM barriers. Each phase =
// {reads; stage; [VMW]; BAR; MM} -- next phase's ds_reads issue while this
// phase's MFMAs execute. VMW before the phase BAR preserves write-visibility
// (VMW -> BAR -> read); Af0/Af1 split kills the LDA(ph2)/MM(0,1) register WAR.
// Schedule-family bracket (12 variants): 8BAR=39%, 4BAR=43%, 2BAR=33%,
// 1BAR/3buf=37%, MM-lag=40%, up-front-reads=37%, 32x32=36%, st_16x32=36%,
// 2blk/CU=38%, BK32=37%, 4-fat-waves=32% -> 4BAR same-phase 8-wave is the peak.
// Swizzle: byte ^= ((storage_row & 7) << 4); both-sides. Conflict-free (r5).

#define BAR __builtin_amdgcn_s_barrier()
#define VMW(n) asm volatile("s_waitcnt vmcnt(" #n ")" ::: "memory")

#define STGA(i, kt, buf) gld16(gA[i] + (size_t)(kt) * 128, &ldsA[buf][((i) << 12) + (w << 9)])
#define STGB(i, kt, buf) gld16(gB[i] + (size_t)(kt) * 128, &ldsB[buf][((i) << 12) + (w << 9)])

#define LDA(dst, mh) do { int ra_ = (wm << 1) | (mh);                              \
    const char* base_ = (const char*)&ldsA[cur][0]                                 \
        + (((((ra_ & 1) << 1) | (ra_ >> 1))) << 13) + laneRow;                     \
    _Pragma("unroll") for (int m_ = 0; m_ < 4; ++m_) {                             \
        dst[m_][0] = *(const bf16x8*)(base_ + (m_ << 11) + ck0);                   \
        dst[m_][1] = *(const bf16x8*)(base_ + (m_ << 11) + ck1); } } while (0)

#define LDB(nh) do { const char* base_ = (const char*)&ldsB[cur][0]                \
        + ((nh) << 14) + (wn << 12) + laneRow;                                     \
    _Pragma("unroll") for (int n_ = 0; n_ < 2; ++n_) {                             \
        Bf[(nh) * 2 + n_][0] = *(const bf16x8*)(base_ + (n_ << 11) + ck0);         \
        Bf[(nh) * 2 + n_][1] = *(const bf16x8*)(base_ + (n_ << 11) + ck1); } } while (0)

#define MM(Asrc, mh, nh) do { __builtin_amdgcn_s_setprio(1);                       \
    _Pragma("unroll") for (int m_ = 0; m_ < 4; ++m_)                               \
    _Pragma("unroll") for (int n_ = 0; n_ < 2; ++n_)                               \
    _Pragma("unroll") for (int k_ = 0; k_ < 2; ++k_)                               \
        acc[(mh) * 4 + m_][(nh) * 2 + n_] = __builtin_amdgcn_mfma_f32_16x16x32_bf16( \
            Asrc[m_][k_], Bf[(nh) * 2 + n_][k_], acc[(mh) * 4 + m_][(nh) * 2 + n_], 0, 0, 0); \
    __builtin_amdgcn_s_setprio(0); } while (0)

__global__ __launch_bounds__(512, 2) void ema_gemm_kernel(
        const short* __restrict__ Sb, const short* __restrict__ Wb,
        const float* __restrict__ bias, float* __restrict__ out) {
    __shared__ short ldsA[2][16384];   // 64 KiB
    __shared__ short ldsB[2][16384];   // 64 KiB

    int bid = blockIdx.x;
    int swz = ((bid & 7) << 6) | (bid >> 3);   // XCD swizzle, bijective (512 % 8 == 0)
    int tm = swz >> 3;                 // 0..63
    int tn = swz & 7;                  // 0..7

    int tid  = threadIdx.x;
    int lane = tid & 63;
    int w    = tid >> 6;               // 0..7
    int wm   = w >> 2;                 // 0..1
    int wn   = w & 3;                  // 0..3

    const int K2 = H_ * 2;             // row stride in bytes (4096)
    int rowA = tm << 8;
    int rowB = tn << 8;

    // ---- staging source pointers (per-lane, pre-swizzled global addresses) ----
    int rowoff = (w << 3) + (lane >> 3);                 // 0..63 within an 8KB issue
    int colb   = (((lane & 7) ^ (lane >> 3)) << 4);      // inverse-swizzled k-byte
    const char* SbB = (const char*)Sb;
    const char* WbB = (const char*)Wb;
    const char* gA[4];
    const char* gB[4];
    #pragma unroll
    for (int i = 0; i < 4; ++i) {
        int lq = ((i & 1) << 1) | (i >> 1);              // storage slot -> logical A quarter
        gA[i] = SbB + (size_t)(rowA + lq * 64 + rowoff) * K2 + colb;
        int pos = 2 * i + (w >> 2);                      // B storage 32-row slot
        int ls  = ((pos & 3) << 1) | (pos >> 2);         // -> logical slice
        gB[i] = WbB + (size_t)(rowB + ls * 32 + ((w & 3) << 3) + (lane >> 3)) * K2 + colb;
    }

    // ---- fragment ds_read offsets (swizzled) ----
    int laneRow = (lane & 15) << 7;
    int ck0 = (((lane >> 4)) ^ (lane & 7)) << 4;
    int ck1 = ((4 + (lane >> 4)) ^ (lane & 7)) << 4;

    f32x4 acc[8][4];
    #pragma unroll
    for (int i = 0; i < 8; ++i)
        #pragma unroll
        for (int j = 0; j < 4; ++j)
            acc[i][j] = (f32x4){0.f, 0.f, 0.f, 0.f};
    bf16x8 Af0[4][2], Af1[4][2], Bf[4][2];

    int colg = (tn << 8) + (wn << 6) + (lane & 15);
    float bb[4];
    #pragma unroll
    for (int n = 0; n < 4; ++n) bb[n] = bias[colg + (n << 4)];

    // ---- prologue: tile0 full + tile1 first halves; leave 6 loads in flight ----
    STGA(0, 0, 0); STGA(1, 0, 0); STGB(0, 0, 0); STGB(1, 0, 0);   // A1st(0), B1st(0)
    STGA(2, 0, 0); STGA(3, 0, 0); STGB(2, 0, 0); STGB(3, 0, 0);   // A2nd(0), B2nd(0)
    STGA(0, 1, 1); STGA(1, 1, 1); STGB(0, 1, 1); STGB(1, 1, 1);   // A1st(1), B1st(1)
    VMW(6);
    BAR;

    for (int t = 0; t < NKT; ++t) {
        int cur = t & 1, nxt = cur ^ 1;
        bool i01 = (t < NKT - 1), i23 = (t < NKT - 2);
        // phase 0: reads (mh0 frags + B nh0); stage A2nd(t+1); VMW; BAR; MFMA
        LDA(Af0, 0); LDB(0);
        if (i01) { STGA(2, t + 1, nxt); STGA(3, t + 1, nxt); VMW(6); }
        BAR;
        MM(Af0, 0, 0);
        // phase 1: reads B nh1; stage B2nd(t+1); BAR; MFMA
        LDB(1);
        if (i01) { STGB(2, t + 1, nxt); STGB(3, t + 1, nxt); }
        BAR;
        MM(Af0, 0, 1);
        // phase 2: reads mh1 frags; stage A1st(t+2) into dead cur; BAR; MFMA
        LDA(Af1, 1);
        if (i23) { STGA(0, t + 2, cur); STGA(1, t + 2, cur); }
        BAR;
        MM(Af1, 1, 0);
        // phase 3: stage B1st(t+2) into dead cur; VMW; BAR; MFMA
        if (i23)                { STGB(0, t + 2, cur); STGB(1, t + 2, cur); VMW(6); }
        else if (t == NKT - 2)  { VMW(0); }   // entering last tile: drain
        BAR;
        MM(Af1, 1, 1);
    }

    // ---- epilogue: C/D layout col=lane&15, row=(lane>>4)*4+q ----
    int rowg = (tm << 8) + (wm << 7) + ((lane >> 4) << 2);
    #pragma unroll
    for (int m = 0; m < 8; ++m) {
        #pragma unroll
        for (int n = 0; n < 4; ++n) {
            int c = colg + (n << 4);
            size_t rb = (size_t)(rowg + (m << 4)) << 11;
            #pragma unroll
            for (int q = 0; q < 4; ++q)
                out[rb + ((size_t)q << 11) + c] = acc[m][n][q] + bb[n];
        }
    }
}

extern "C" void kernel_launch(void* const* d_in, const int* in_sizes, int n_in,
                              void* d_out, int out_size, void* d_ws, size_t ws_size,
                              hipStream_t stream) {
    const float* x    = (const float*)d_in[0];   // [B,S,H] f32
    const float* W    = (const float*)d_in[1];   // [H,H] f32
    const float* bias = (const float*)d_in[2];   // [H] f32
    float* out = (float*)d_out;                  // [B,S,H] f32

    char* ws = (char*)d_ws;
    size_t s_bytes = (size_t)B_ * S_ * H_ * 2;   // 67.1 MB bf16 s
    size_t w_bytes = (size_t)H_ * H_ * 2;        // 8.4 MB bf16 W
    unsigned short* s_bf  = (unsigned short*)ws;
    short*          w_bf  = (short*)(ws + s_bytes);
    float*          carry = (float*)(ws + s_bytes + w_bytes);  // 8*16*2048 f32 = 1 MB

    ema_cast_w<<<(H_ * H_) / 1024, 256, 0, stream>>>(W, w_bf);
    ema_carry_kernel<<<B_ * NCH * (H_ / 512), 256, 0, stream>>>(x, carry);
    ema_apply_kernel<<<B_ * NCH * (H_ / 512), 256, 0, stream>>>(x, carry, s_bf);
    ema_gemm_kernel<<<(16384 / 256) * (2048 / 256), 512, 0, stream>>>(
        (const short*)s_bf, w_bf, bias, out);
}